// Round 2
// baseline (557.718 us; speedup 1.0000x reference)
//
#include <hip/hip_runtime.h>
#include <hip/hip_bf16.h>

#define LRALPHA 0.2f
#define LOG2E 1.4426950408889634f

typedef __attribute__((ext_vector_type(8))) short frag_ab;   // 8 x bf16
typedef __attribute__((ext_vector_type(4))) float frag_cd;   // 4 x f32
typedef int   iv4 __attribute__((ext_vector_type(4)));
typedef float fv4 __attribute__((ext_vector_type(4)));
typedef unsigned int uv4 __attribute__((ext_vector_type(4)));
typedef unsigned int uv2 __attribute__((ext_vector_type(2)));

static __device__ __forceinline__ unsigned short f2bf(float f) {
  __hip_bfloat16 b = __float2bfloat16(f);
  unsigned short u;
  __builtin_memcpy(&u, &b, 2);
  return u;
}

// exp2 (s1/s2 are pre-scaled by log2(e) in gat_hproj)
#if __has_builtin(__builtin_amdgcn_exp2f)
#define EXP2F(x) __builtin_amdgcn_exp2f(x)
#else
#define EXP2F(x) exp2f(x)
#endif

// 2 x f32 -> packed 2 x bf16 (RNE), gfx950-native
static __device__ __forceinline__ unsigned cvt_pk_bf16(float lo, float hi) {
  unsigned r;
  asm("v_cvt_pk_bf16_f32 %0, %1, %2" : "=v"(r) : "v"(lo), "v"(hi));
  return r;
}

// Barrier ordering LDS only: lgkmcnt(0) + s_barrier, NO vmcnt drain —
// keeps the dist-2 adj prefetch in flight across iterations.
static __device__ __forceinline__ void block_sync_lds() {
  __builtin_amdgcn_sched_barrier(0);
  asm volatile("s_waitcnt lgkmcnt(0)" ::: "memory");
  __builtin_amdgcn_s_barrier();
  __builtin_amdgcn_sched_barrier(0);
}

// 4 elements: w = exp2(lrelu(s1r + s2[j]) - mr), masked by adj; Z from f32 w.
static __device__ __forceinline__ uv2 make_w4(iv4 ca, fv4 cv,
                                              float s1r, float mr, float& zloc) {
  float w[4];
#pragma unroll
  for (int e = 0; e < 4; ++e) {
    float ee = s1r + cv[e];                  // log2 units
    ee = fmaxf(ee, LRALPHA * ee);            // leakyrelu (slope<1)
    float ww = EXP2F(ee - mr);               // <= 1 by construction
    ww = ca[e] ? ww : 0.f;
    zloc += ww;
    w[e] = ww;
  }
  uv2 r;
  r[0] = cvt_pk_bf16(w[0], w[1]);
  r[1] = cvt_pk_bf16(w[2], w[3]);
  return r;
}

// ---------------- Kernel A: h = X@W (fp32), s1/s2 (pre-scaled by log2 e), hT = bf16(h)^T
__global__ __launch_bounds__(256, 4) void gat_hproj(
    const float* __restrict__ X, const float* __restrict__ W,
    const float* __restrict__ avec,
    float* __restrict__ s1, float* __restrict__ s2,
    unsigned short* __restrict__ hT) {
  const int tid = threadIdx.x;
  const int row0 = blockIdx.x * 16;
  const float* Xb = X + (size_t)row0 * 256;
  const int c = tid;  // output column 0..255

  float acc[16];
#pragma unroll
  for (int r = 0; r < 16; ++r) acc[r] = 0.f;

  for (int k = 0; k < 256; k += 4) {
    const float w0 = W[(k + 0) * 256 + c];
    const float w1 = W[(k + 1) * 256 + c];
    const float w2 = W[(k + 2) * 256 + c];
    const float w3 = W[(k + 3) * 256 + c];
#pragma unroll
    for (int r = 0; r < 16; ++r) {
      acc[r] = fmaf(Xb[r * 256 + k + 0], w0, acc[r]);
      acc[r] = fmaf(Xb[r * 256 + k + 1], w1, acc[r]);
      acc[r] = fmaf(Xb[r * 256 + k + 2], w2, acc[r]);
      acc[r] = fmaf(Xb[r * 256 + k + 3], w3, acc[r]);
    }
  }

  // hT (bf16, [f][j] layout): thread writes 16 contiguous bf16 in row c
  alignas(16) unsigned short hu[16];
#pragma unroll
  for (int r = 0; r < 16; ++r) hu[r] = f2bf(acc[r]);
  uv4* hdst = (uv4*)(hT + (size_t)c * 8192 + row0);
  hdst[0] = *(const uv4*)&hu[0];
  hdst[1] = *(const uv4*)&hu[8];

  // s1/s2: reduce acc[r]*a over 256 threads (=columns); scaled by log2(e).
  const float a1c = avec[c];
  const float a2c = avec[256 + c];
  const int lane = tid & 63, wave = tid >> 6;
  __shared__ float r1[4][16], r2[4][16];
#pragma unroll
  for (int r = 0; r < 16; ++r) {
    float v1 = acc[r] * a1c;
    float v2 = acc[r] * a2c;
#pragma unroll
    for (int off = 32; off > 0; off >>= 1) {
      v1 += __shfl_down(v1, off);
      v2 += __shfl_down(v2, off);
    }
    if (lane == 0) { r1[wave][r] = v1; r2[wave][r] = v2; }
  }
  __syncthreads();
  if (tid < 16) {
    s1[row0 + tid] = (r1[0][tid] + r1[1][tid] + r1[2][tid] + r1[3][tid]) * LOG2E;
    s2[row0 + tid] = (r2[0][tid] + r2[1][tid] + r2[2][tid] + r2[3][tid]) * LOG2E;
  }
}

// ---------------- Kernel B: fully-fused masked-softmax + P@h + 1/Z + ELU
// 256 blocks x 512 threads; block = 32 rows x ALL 8192 cols (128 iters of 64).
// Z is complete in-block -> divide + elu + write out directly (no pacc
// round-trip, no combine kernel, no separate s2max kernel).
__global__ __launch_bounds__(512, 2) void gat_attn_full(
    const int* __restrict__ adj, const unsigned short* __restrict__ hT,
    const float* __restrict__ s1, const float* __restrict__ s2,
    float* __restrict__ out) {
  const int bid = blockIdx.x;  // 0..255
  const int row0 = bid * 32;
  const int tid = threadIdx.x;
  const int wave = tid >> 6, lane = tid & 63;
  const int ln16 = lane & 15, quad = lane >> 4;

  __shared__ __align__(16) unsigned short P[2][32][72];  // double-buffered, +8 pad
  __shared__ float Zred[32][16];
  __shared__ float wred[8];
  __shared__ float Zinv[32];

  // ---- block-local global max of s2 (32 KB, L2-hot; bound for exp range)
  float m = -1e30f;
  for (int i = tid; i < 8192; i += 512) m = fmaxf(m, s2[i]);
#pragma unroll
  for (int off = 32; off > 0; off >>= 1) m = fmaxf(m, __shfl_down(m, off));
  if (lane == 0) wred[wave] = m;
  __syncthreads();
  float s2m = wred[0];
#pragma unroll
  for (int wv = 1; wv < 8; ++wv) s2m = fmaxf(s2m, wred[wv]);

  const int r = tid >> 4;   // 0..31  (row within block)
  const int cg = tid & 15;  // 0..15  (4 cols each)
  const float s1r = s1[row0 + r];
  const float tmv = s1r + s2m;
  const float mr = tmv >= 0.f ? tmv : LRALPHA * tmv;  // >= row max of lrelu

  const int* adjRow = adj + (size_t)(row0 + r) * 8192 + cg * 4;
  const float* s2p = s2 + cg * 4;

  frag_cd acc[2][2];
  const frag_cd fz = {0.f, 0.f, 0.f, 0.f};
#pragma unroll
  for (int mi = 0; mi < 2; ++mi)
#pragma unroll
    for (int ni = 0; ni < 2; ++ni) acc[mi][ni] = fz;

  float zloc = 0.f;
  const int NIT = 128;

  // preamble: w(0) -> P[0]; prefetch adj/s2 for jt=1
  {
    iv4 ca = __builtin_nontemporal_load((const iv4*)adjRow);
    fv4 cv = *(const fv4*)s2p;
    *(uv2*)&P[0][r][cg * 4] = make_w4(ca, cv, s1r, mr, zloc);
  }
  iv4 a = __builtin_nontemporal_load((const iv4*)(adjRow + 64));
  fv4 v = *(const fv4*)(s2p + 64);
  block_sync_lds();

  for (int jt = 0; jt < NIT; ++jt) {
    const int cur = jt & 1, nxt = cur ^ 1;
    const size_t jbase = (size_t)jt * 64;

    // B-fragments for THIS iter — issue first (L2 latency overlaps w-compute)
    frag_ab bf[2][2];  // [kk][ni]
#pragma unroll
    for (int kk = 0; kk < 2; ++kk)
#pragma unroll
      for (int ni = 0; ni < 2; ++ni) {
        const int f = wave * 32 + ni * 16 + ln16;
        bf[kk][ni] = *(const frag_ab*)(hT + (size_t)f * 8192 + jbase + kk * 32 + quad * 8);
      }

    // prefetch adj/s2 for jt+2
    iv4 a2; fv4 v2;
    if (jt + 2 < NIT) {
      const int o = (jt + 2) * 64;
      a2 = __builtin_nontemporal_load((const iv4*)(adjRow + o));
      v2 = *(const fv4*)(s2p + o);
    }

    // compute w(jt+1) -> P[nxt] (overlaps MFMA of jt; barrier-safe with dbuf)
    if (jt + 1 < NIT) {
      *(uv2*)&P[nxt][r][cg * 4] = make_w4(a, v, s1r, mr, zloc);
    }

    // A-fragments from P[cur] + MFMA
#pragma unroll
    for (int kk = 0; kk < 2; ++kk) {
      frag_ab af[2];
#pragma unroll
      for (int mi = 0; mi < 2; ++mi)
        af[mi] = *(const frag_ab*)&P[cur][mi * 16 + ln16][kk * 32 + quad * 8];
#pragma unroll
      for (int mi = 0; mi < 2; ++mi)
#pragma unroll
        for (int ni = 0; ni < 2; ++ni)
          acc[mi][ni] = __builtin_amdgcn_mfma_f32_16x16x32_bf16(
              af[mi], bf[kk][ni], acc[mi][ni], 0, 0, 0);
    }
    block_sync_lds();
    a = a2; v = v2;
  }

  // ---- Z reduce (full row is in-block) -> 1/Z
  Zred[r][cg] = zloc;
  __syncthreads();
  if (tid < 32) {
    float z = 0.f;
#pragma unroll
    for (int q = 0; q < 16; ++q) z += Zred[tid][q];
    Zinv[tid] = 1.f / z;
  }
  __syncthreads();

  // ---- epilogue: divide, elu, store output directly
  // C/D layout: col(feature)=lane&15, row=quad*4+reg
  float* outb = out + (size_t)row0 * 256;
#pragma unroll
  for (int mi = 0; mi < 2; ++mi) {
#pragma unroll
    for (int ni = 0; ni < 2; ++ni) {
      const int f = wave * 32 + ni * 16 + ln16;
#pragma unroll
      for (int reg = 0; reg < 4; ++reg) {
        const int grow = mi * 16 + quad * 4 + reg;
        const float vv = acc[mi][ni][reg] * Zinv[grow];
        const float o = vv > 0.f ? vv : expm1f(vv);
        __builtin_nontemporal_store(o, outb + (size_t)grow * 256 + f);
      }
    }
  }
}

extern "C" void kernel_launch(void* const* d_in, const int* in_sizes, int n_in,
                              void* d_out, int out_size, void* d_ws, size_t ws_size,
                              hipStream_t stream) {
  const float* X = (const float*)d_in[0];
  const int* adj = (const int*)d_in[1];
  const float* W = (const float*)d_in[2];
  const float* avec = (const float*)d_in[3];
  float* out = (float*)d_out;

  float* wsf = (float*)d_ws;
  float* s1 = wsf;                                   // 8192
  float* s2 = wsf + 8192;                            // 8192
  unsigned short* hT = (unsigned short*)(wsf + 16384);  // 8192*256 bf16 = 4 MB

  hipLaunchKernelGGL(gat_hproj, dim3(512), dim3(256), 0, stream, X, W, avec, s1, s2, hT);
  hipLaunchKernelGGL(gat_attn_full, dim3(256), dim3(512), 0, stream, adj, hT, s1, s2, out);
}

// Round 5
// 520.409 us; speedup vs baseline: 1.0717x; 1.0717x over previous
//
#include <hip/hip_runtime.h>
#include <hip/hip_bf16.h>

#define LRALPHA 0.2f
#define LOG2E 1.4426950408889634f

typedef __attribute__((ext_vector_type(8))) short frag_ab;   // 8 x bf16
typedef __attribute__((ext_vector_type(4))) float frag_cd;   // 4 x f32
typedef int   iv4 __attribute__((ext_vector_type(4)));
typedef float fv4 __attribute__((ext_vector_type(4)));
typedef int   iv2 __attribute__((ext_vector_type(2)));
typedef float fv2 __attribute__((ext_vector_type(2)));
typedef unsigned int uv4 __attribute__((ext_vector_type(4)));

static __device__ __forceinline__ unsigned short f2bf(float f) {
  __hip_bfloat16 b = __float2bfloat16(f);
  unsigned short u;
  __builtin_memcpy(&u, &b, 2);
  return u;
}

// exp2 (s1/s2 are pre-scaled by log2(e) in gat_hproj)
#if __has_builtin(__builtin_amdgcn_exp2f)
#define EXP2F(x) __builtin_amdgcn_exp2f(x)
#else
#define EXP2F(x) exp2f(x)
#endif

// 2 x f32 -> packed 2 x bf16 (RNE), gfx950-native
static __device__ __forceinline__ unsigned cvt_pk_bf16(float lo, float hi) {
  unsigned r;
  asm("v_cvt_pk_bf16_f32 %0, %1, %2" : "=v"(r) : "v"(lo), "v"(hi));
  return r;
}

// Barrier ordering LDS only: lgkmcnt(0) + s_barrier, NO vmcnt drain —
// keeps adj (dist-2) and hT (dist-1) prefetches in flight across iterations.
static __device__ __forceinline__ void block_sync_lds() {
  __builtin_amdgcn_sched_barrier(0);
  asm volatile("s_waitcnt lgkmcnt(0)" ::: "memory");
  __builtin_amdgcn_s_barrier();
  __builtin_amdgcn_sched_barrier(0);
}

// 2 elements: w = exp2(lrelu(s1r + s2[j]) - mr), masked by adj; Z from f32 w.
static __device__ __forceinline__ unsigned make_w2(iv2 ca, fv2 cv,
                                                   float s1r, float mr, float& zloc) {
  float w[2];
#pragma unroll
  for (int e = 0; e < 2; ++e) {
    float ee = s1r + cv[e];                  // log2 units
    ee = fmaxf(ee, LRALPHA * ee);            // leakyrelu (slope<1)
    float ww = EXP2F(ee - mr);               // <= 1 by construction
    ww = ca[e] ? ww : 0.f;
    zloc += ww;
    w[e] = ww;
  }
  return cvt_pk_bf16(w[0], w[1]);
}

// ---------------- Kernel A: h = X@W (fp32), s1/s2 (pre-scaled by log2 e), hT = bf16(h)^T
__global__ __launch_bounds__(256, 4) void gat_hproj(
    const float* __restrict__ X, const float* __restrict__ W,
    const float* __restrict__ avec,
    float* __restrict__ s1, float* __restrict__ s2,
    unsigned short* __restrict__ hT) {
  const int tid = threadIdx.x;
  const int row0 = blockIdx.x * 16;
  const float* Xb = X + (size_t)row0 * 256;
  const int c = tid;  // output column 0..255

  float acc[16];
#pragma unroll
  for (int r = 0; r < 16; ++r) acc[r] = 0.f;

  for (int k = 0; k < 256; k += 4) {
    const float w0 = W[(k + 0) * 256 + c];
    const float w1 = W[(k + 1) * 256 + c];
    const float w2 = W[(k + 2) * 256 + c];
    const float w3 = W[(k + 3) * 256 + c];
#pragma unroll
    for (int r = 0; r < 16; ++r) {
      acc[r] = fmaf(Xb[r * 256 + k + 0], w0, acc[r]);
      acc[r] = fmaf(Xb[r * 256 + k + 1], w1, acc[r]);
      acc[r] = fmaf(Xb[r * 256 + k + 2], w2, acc[r]);
      acc[r] = fmaf(Xb[r * 256 + k + 3], w3, acc[r]);
    }
  }

  // hT (bf16, [f][j] layout): thread writes 16 contiguous bf16 in row c
  alignas(16) unsigned short hu[16];
#pragma unroll
  for (int r = 0; r < 16; ++r) hu[r] = f2bf(acc[r]);
  uv4* hdst = (uv4*)(hT + (size_t)c * 8192 + row0);
  hdst[0] = *(const uv4*)&hu[0];
  hdst[1] = *(const uv4*)&hu[8];

  // s1/s2: reduce acc[r]*a over 256 threads (=columns); scaled by log2(e).
  const float a1c = avec[c];
  const float a2c = avec[256 + c];
  const int lane = tid & 63, wave = tid >> 6;
  __shared__ float r1[4][16], r2[4][16];
#pragma unroll
  for (int r = 0; r < 16; ++r) {
    float v1 = acc[r] * a1c;
    float v2 = acc[r] * a2c;
#pragma unroll
    for (int off = 32; off > 0; off >>= 1) {
      v1 += __shfl_down(v1, off);
      v2 += __shfl_down(v2, off);
    }
    if (lane == 0) { r1[wave][r] = v1; r2[wave][r] = v2; }
  }
  __syncthreads();
  if (tid < 16) {
    s1[row0 + tid] = (r1[0][tid] + r1[1][tid] + r1[2][tid] + r1[3][tid]) * LOG2E;
    s2[row0 + tid] = (r2[0][tid] + r2[1][tid] + r2[2][tid] + r2[3][tid]) * LOG2E;
  }
}

// ---------------- Kernel B: fully-fused masked-softmax + P@h + 1/Z + ELU
// 256 blocks x 1024 threads (16 waves); block = 32 rows x ALL 8192 cols.
// 16 waves/CU (4/SIMD) for latency hiding; hT B-frags double-buffered in
// registers one iteration ahead; adj/s2 prefetched 2 ahead (nontemporal);
// LDS-only barrier (vmcnt never drained in the loop).
__global__ __launch_bounds__(1024, 4) void gat_attn_full(
    const int* __restrict__ adj, const unsigned short* __restrict__ hT,
    const float* __restrict__ s1, const float* __restrict__ s2,
    float* __restrict__ out) {
  const int bid = blockIdx.x;  // 0..255
  const int row0 = bid * 32;
  const int tid = threadIdx.x;
  const int wave = tid >> 6, lane = tid & 63;
  const int ln16 = lane & 15, quad = lane >> 4;

  __shared__ __align__(16) unsigned short P[2][32][72];  // double-buffered, +8 pad
  __shared__ float Zred[32][32];
  __shared__ float wred[16];
  __shared__ float Zinv[32];

  // ---- block-local global max of s2 (32 KB, L2-hot; bound for exp range)
  float m = -1e30f;
  for (int i = tid; i < 8192; i += 1024) m = fmaxf(m, s2[i]);
#pragma unroll
  for (int off = 32; off > 0; off >>= 1) m = fmaxf(m, __shfl_down(m, off));
  if (lane == 0) wred[wave] = m;
  __syncthreads();
  float s2m = wred[0];
#pragma unroll
  for (int wv = 1; wv < 16; ++wv) s2m = fmaxf(s2m, wred[wv]);

  const int r = tid >> 5;   // 0..31  (row within block)
  const int cg = tid & 31;  // 0..31  (2 cols each)
  const float s1r = s1[row0 + r];
  const float tmv = s1r + s2m;
  const float mr = tmv >= 0.f ? tmv : LRALPHA * tmv;  // >= row max of lrelu

  const int* adjRow = adj + (size_t)(row0 + r) * 8192 + cg * 2;
  const float* s2p = s2 + cg * 2;
  const unsigned short* hTw = hT + (size_t)(wave * 16 + ln16) * 8192 + quad * 8;

  frag_cd acc[2];
  const frag_cd fz = {0.f, 0.f, 0.f, 0.f};
  acc[0] = fz; acc[1] = fz;

  float zloc = 0.f;
  const int NIT = 128;

  // preamble: w(0) -> P[0]; prefetch adj/s2 for jt=1; bf frags for jt=0
  {
    iv2 ca = __builtin_nontemporal_load((const iv2*)adjRow);
    fv2 cv = *(const fv2*)s2p;
    *(unsigned*)&P[0][r][cg * 2] = make_w2(ca, cv, s1r, mr, zloc);
  }
  iv2 a = __builtin_nontemporal_load((const iv2*)(adjRow + 64));
  fv2 v = *(const fv2*)(s2p + 64);
  frag_ab bfC0 = *(const frag_ab*)(hTw + 0);
  frag_ab bfC1 = *(const frag_ab*)(hTw + 32);
  block_sync_lds();

  for (int jt = 0; jt < NIT; ++jt) {
    const int cur = jt & 1, nxt = cur ^ 1;

    // hT B-frags for NEXT iter — issued a full iteration before use
    frag_ab bfN0, bfN1;
    if (jt + 1 < NIT) {
      const size_t jn = (size_t)(jt + 1) * 64;
      bfN0 = *(const frag_ab*)(hTw + jn);
      bfN1 = *(const frag_ab*)(hTw + jn + 32);
    }

    // prefetch adj/s2 for jt+2
    iv2 a2; fv2 v2;
    if (jt + 2 < NIT) {
      const int o = (jt + 2) * 64;
      a2 = __builtin_nontemporal_load((const iv2*)(adjRow + o));
      v2 = *(const fv2*)(s2p + o);
    }

    // compute w(jt+1) -> P[nxt] (overlaps MFMA of jt; barrier-safe with dbuf)
    if (jt + 1 < NIT) {
      *(unsigned*)&P[nxt][r][cg * 2] = make_w2(a, v, s1r, mr, zloc);
    }

    // A-fragments from P[cur] + MFMA (bf frags loaded LAST iteration).
    // B-slice pairing: kk=0 -> bfC0 for BOTH row-blocks; kk=1 -> bfC1.
    {
      frag_ab af0 = *(const frag_ab*)&P[cur][ln16][quad * 8];          // rows 0-15,  kk=0
      frag_ab af1 = *(const frag_ab*)&P[cur][16 + ln16][quad * 8];     // rows 16-31, kk=0
      acc[0] = __builtin_amdgcn_mfma_f32_16x16x32_bf16(af0, bfC0, acc[0], 0, 0, 0);
      acc[1] = __builtin_amdgcn_mfma_f32_16x16x32_bf16(af1, bfC0, acc[1], 0, 0, 0);
      frag_ab af2 = *(const frag_ab*)&P[cur][ln16][32 + quad * 8];     // rows 0-15,  kk=1
      frag_ab af3 = *(const frag_ab*)&P[cur][16 + ln16][32 + quad * 8];// rows 16-31, kk=1
      acc[0] = __builtin_amdgcn_mfma_f32_16x16x32_bf16(af2, bfC1, acc[0], 0, 0, 0);
      acc[1] = __builtin_amdgcn_mfma_f32_16x16x32_bf16(af3, bfC1, acc[1], 0, 0, 0);
    }
    block_sync_lds();
    bfC0 = bfN0; bfC1 = bfN1;
    a = a2; v = v2;
  }

  // ---- Z reduce (full row is in-block) -> 1/Z
  Zred[r][cg] = zloc;
  __syncthreads();
  if (tid < 32) {
    float z = 0.f;
#pragma unroll
    for (int q = 0; q < 32; ++q) z += Zred[tid][q];
    Zinv[tid] = 1.f / z;
  }
  __syncthreads();

  // ---- epilogue: divide, elu, store output directly
  // C/D layout: col(feature)=lane&15, row=quad*4+reg (+ mi*16)
  float* outb = out + (size_t)row0 * 256;
  const int f = wave * 16 + ln16;
#pragma unroll
  for (int mi = 0; mi < 2; ++mi) {
#pragma unroll
    for (int reg = 0; reg < 4; ++reg) {
      const int grow = mi * 16 + quad * 4 + reg;
      const float vv = acc[mi][reg] * Zinv[grow];
      const float o = vv > 0.f ? vv : expm1f(vv);
      __builtin_nontemporal_store(o, outb + (size_t)grow * 256 + f);
    }
  }
}

extern "C" void kernel_launch(void* const* d_in, const int* in_sizes, int n_in,
                              void* d_out, int out_size, void* d_ws, size_t ws_size,
                              hipStream_t stream) {
  const float* X = (const float*)d_in[0];
  const int* adj = (const int*)d_in[1];
  const float* W = (const float*)d_in[2];
  const float* avec = (const float*)d_in[3];
  float* out = (float*)d_out;

  float* wsf = (float*)d_ws;
  float* s1 = wsf;                                   // 8192
  float* s2 = wsf + 8192;                            // 8192
  unsigned short* hT = (unsigned short*)(wsf + 16384);  // 8192*256 bf16 = 4 MB

  hipLaunchKernelGGL(gat_hproj, dim3(512), dim3(256), 0, stream, X, W, avec, s1, s2, hT);
  hipLaunchKernelGGL(gat_attn_full, dim3(256), dim3(1024), 0, stream, adj, hT, s1, s2, out);
}